// Round 5
// baseline (156.916 us; speedup 1.0000x reference)
//
#include <hip/hip_runtime.h>

#define BB 128
#define II 512
#define HH 256
#define OO 32
#define FF 16
#define OF 512
#define CI 64          // i-rows per route block
#define NP 8           // partials per b (II / CI)
#define CSTR 72        // c2 LDS row stride (ushorts, 144 B) [R1-verified]
#define WLSTR 17       // W_o LDS row stride (floats, odd -> conflict-free)
#define XBSTR 264      // cx bounce row stride (ushorts; 132 dw === 4 mod 32)

typedef __attribute__((ext_vector_type(8))) short short8;   // 8 bf16
typedef __attribute__((ext_vector_type(4))) float floatx4;  // MFMA C/D

__device__ __forceinline__ ushort f2bf(float f) {           // RTN-even
  unsigned u = __float_as_uint(f);
  u += 0x7FFFu + ((u >> 16) & 1u);
  return (ushort)(u >> 16);
}
__device__ __forceinline__ float bf2f(ushort u) {
  return __uint_as_float(((unsigned)u) << 16);
}
// 16B-granule swizzle key for row i (R1-verified bijection).
__device__ __forceinline__ int swzrow(int i) {
  return (i & 7) ^ (((i >> 3) & 3) << 1);
}

// ---------- Kernel 1: x -> bf16 (swizzled) + per-tile column sums ----------
// grid = B*NP (1024), block = 256. UNCHANGED from R1 (verified).
__global__ __launch_bounds__(256) void k_prep(
    const float* __restrict__ x, ushort* __restrict__ x16,
    float* __restrict__ xsum_part) {
  __shared__ float4 red[4][64];
  int t = threadIdx.x;
  int blk = blockIdx.x;                 // b*8 + p
  int c4 = t & 63, grp = t >> 6;
  const float* xg = x + (size_t)blk * CI * HH;
  ushort* x16g = x16 + (size_t)blk * CI * HH;
  int g = c4 >> 1, s4 = (c4 & 1) * 4;
  float4 sum = make_float4(0.f, 0.f, 0.f, 0.f);
#pragma unroll
  for (int j = 0; j < 16; ++j) {
    int row = j * 4 + grp;
    float4 v4 = *(const float4*)(xg + (size_t)row * HH + c4 * 4);
    sum.x += v4.x; sum.y += v4.y; sum.z += v4.z; sum.w += v4.w;
    ushort4 u;
    u.x = f2bf(v4.x); u.y = f2bf(v4.y); u.z = f2bf(v4.z); u.w = f2bf(v4.w);
    *(ushort4*)&x16g[row * HH + (((g ^ swzrow(row)) << 3) + s4)] = u;
  }
  red[grp][c4] = sum;
  __syncthreads();
  if (t < 64) {
    float4 s0 = red[0][t], s1 = red[1][t], s2 = red[2][t], s3 = red[3][t];
    s0.x += s1.x + s2.x + s3.x; s0.y += s1.y + s2.y + s3.y;
    s0.z += s1.z + s2.z + s3.z; s0.w += s1.w + s2.w + s3.w;
    *(float4*)&xsum_part[(size_t)blk * HH + t * 4] = s0;
  }
}

// ---------- Kernel 2: v1 = squash(xsum @ W / 32) -> wvT16 ------------------
// grid = B*O (4096), block = 256. UNCHANGED from R4 (verified).
__global__ __launch_bounds__(256) void k_v1(
    const float* __restrict__ xsum_part, const float* __restrict__ W,
    ushort* __restrict__ wvT16) {
  __shared__ float Wl[HH * WLSTR];      // 17.0 KB
  __shared__ float cxs[HH];
  __shared__ float red[4][16];
  __shared__ float vres[FF];
  int t = threadIdx.x;
  int blk = blockIdx.x;                 // b*32 + o
  int b = blk >> 5, o = blk & 31;
  int f = t & 15, hq = t >> 4;
#pragma unroll
  for (int j = 0; j < 16; ++j) {
    int h = hq * 16 + j;
    Wl[h * WLSTR + f] = W[(size_t)h * OF + o * FF + f];
  }
  {
    const float* cp = xsum_part + (size_t)b * NP * HH + t;
    float a = 0.f;
#pragma unroll
    for (int p = 0; p < NP; ++p) a += cp[(size_t)p * HH];
    cxs[t] = a * (1.0f / 32.0f);
  }
  __syncthreads();
  float acc = 0.f;
#pragma unroll
  for (int j = 0; j < 16; ++j)
    acc += cxs[hq * 16 + j] * Wl[(hq * 16 + j) * WLSTR + f];
  acc += __shfl_xor(acc, 16);
  acc += __shfl_xor(acc, 32);
  if ((t & 63) < 16) red[t >> 6][f] = acc;
  __syncthreads();
  if (t < 16) {
    float a2 = red[0][t] + red[1][t] + red[2][t] + red[3][t];
    float n2 = a2 * a2;
#pragma unroll
    for (int mask = 1; mask < 16; mask <<= 1) n2 += __shfl_xor(n2, mask);
    float scale = sqrtf(n2) / (1.f + n2);
    vres[t] = a2 * scale;
  }
  __syncthreads();
  float av = 0.f;
#pragma unroll
  for (int q = 0; q < 16; ++q) av += Wl[t * WLSTR + q] * vres[q];
  wvT16[((size_t)b * OO + o) * HH + t] = f2bf(av);
}

// ---------- Kernel 3: route: x in LDS, wv B-frags in registers -------------
// grid = B*NP (1024), block = 256 (4 waves), LDS 36.6 KB, 3 blocks/CU.
__global__ __launch_bounds__(256, 3) void k_route(
    const ushort* __restrict__ x16, const ushort* __restrict__ wvT16,
    ushort* __restrict__ cxp16) {
  __shared__ alignas(16) ushort xs[CI * HH];     // 32 KB x tile; reused as cx bounce
  __shared__ alignas(16) ushort c2[OO * CSTR];   // 4.5 KB c[o][i]
  int t = threadIdx.x;
  int blk = blockIdx.x;
  int b = blk >> 3;
  int lane = t & 63, w = t >> 6;
  int l16 = lane & 15, quad = lane >> 4;

  // ---- stage x tile: global (pre-swizzled) -> LDS, linear, 16 B/lane ----
  const ushort* gt = x16 + (size_t)blk * (CI * HH);
#pragma unroll
  for (int it = 0; it < 8; ++it) {
    int off = (it * 4 + w) * 512;       // wave-uniform LDS base (1 KiB/instr)
    __builtin_amdgcn_global_load_lds(
        (const __attribute__((address_space(1))) unsigned*)(gt + off + lane * 8),
        (__attribute__((address_space(3))) unsigned*)(&xs[off]), 16, 0, 0);
  }
  // ---- wv B-fragments -> registers (identical across waves; L2-hot).
  // Addressing is R1's verified global path, hoisted out of the K-loop.
  const ushort* wv0 = wvT16 + ((size_t)b * OO + l16) * HH + quad * 8;
  const ushort* wv1 = wv0 + 16 * HH;
  short8 bfr0[8], bfr1[8];
#pragma unroll
  for (int ks = 0; ks < 8; ++ks) {
    bfr0[ks] = *(const short8*)(wv0 + ks * 32);
    bfr1[ks] = *(const short8*)(wv1 + ks * 32);
  }
  asm volatile("s_waitcnt vmcnt(0)" ::: "memory");
  __syncthreads();

  // ---- GEMM1: D[m=i][n=o] = x . wv^T  (K = h = 256, 8 steps) ----
  int i_a = w * 16 + l16;
  int swa = swzrow(i_a);
  const ushort* xrow = &xs[i_a * HH];
  floatx4 acc0 = {0.f, 0.f, 0.f, 0.f}, acc1 = {0.f, 0.f, 0.f, 0.f};
#pragma unroll
  for (int ks = 0; ks < 8; ++ks) {
    short8 af = *(const short8*)(xrow + (((ks * 4 + quad) ^ swa) << 3));
    acc0 = __builtin_amdgcn_mfma_f32_16x16x32_bf16(af, bfr0[ks], acc0, 0, 0, 0);
    acc1 = __builtin_amdgcn_mfma_f32_16x16x32_bf16(af, bfr1[ks], acc1, 0, 0, 0);
  }
  // ---- softmax over o, in-register (rows i = quad*4+r, col o = l16) ----
#pragma unroll
  for (int r = 0; r < 4; ++r) {
    float a0 = acc0[r], a1 = acc1[r];
    float m = fmaxf(a0, a1);
#pragma unroll
    for (int mask = 1; mask < 16; mask <<= 1) m = fmaxf(m, __shfl_xor(m, mask));
    float e0 = __expf(a0 - m), e1 = __expf(a1 - m);
    float s = e0 + e1;
#pragma unroll
    for (int mask = 1; mask < 16; mask <<= 1) s += __shfl_xor(s, mask);
    float inv = 1.f / s;
    int il = w * 16 + quad * 4 + r;
    c2[l16 * CSTR + il] = f2bf(e0 * inv);
    c2[(16 + l16) * CSTR + il] = f2bf(e1 * inv);
  }
  __syncthreads();

  // ---- phase 3: D[m=o][n=h] = c . xT^T  (K = i = 64); d stays in regs ----
  short8 caf[2][2];
#pragma unroll
  for (int mt = 0; mt < 2; ++mt)
#pragma unroll
    for (int ks = 0; ks < 2; ++ks)
      caf[mt][ks] = *(const short8*)&c2[(mt * 16 + l16) * CSTR + ks * 32 + quad * 8];
  floatx4 d0a[4], d1a[4];
#pragma unroll
  for (int hi = 0; hi < 4; ++hi) {
    int ht = w * 4 + hi;
    int hh = ht * 16 + l16;
    int gq = hh >> 3, sub = hh & 7;
    floatx4 d0 = {0.f, 0.f, 0.f, 0.f}, d1 = {0.f, 0.f, 0.f, 0.f};
#pragma unroll
    for (int ks = 0; ks < 2; ++ks) {
      short8 bf;
#pragma unroll
      for (int e = 0; e < 8; ++e) {
        int i = ks * 32 + quad * 8 + e;            // swzrow(i) = e ^ (quad<<1)
        bf[e] = (short)xs[i * HH + (((gq ^ e ^ (quad << 1)) << 3) + sub)];
      }
      d0 = __builtin_amdgcn_mfma_f32_16x16x32_bf16(caf[0][ks], bf, d0, 0, 0, 0);
      d1 = __builtin_amdgcn_mfma_f32_16x16x32_bf16(caf[1][ks], bf, d1, 0, 0, 0);
    }
    d0a[hi] = d0; d1a[hi] = d1;
  }
  __syncthreads();                      // all xs reads complete; xs is now dead

  // ---- bounce cx through xs as [o][XBSTR] bf16, then coalesced stores ----
  {
    ushort* xb = xs;
#pragma unroll
    for (int hi = 0; hi < 4; ++hi) {
      int hcol = w * 64 + hi * 16 + l16;
#pragma unroll
      for (int r = 0; r < 4; ++r) {
        xb[(quad * 4 + r) * XBSTR + hcol] = f2bf(d0a[hi][r]);
        xb[(16 + quad * 4 + r) * XBSTR + hcol] = f2bf(d1a[hi][r]);
      }
    }
  }
  __syncthreads();
  {
    int o = t >> 3, h0 = (t & 7) * 32;
    ushort* dst = cxp16 + (size_t)blk * OO * HH + (size_t)o * HH + h0;
    const ushort* src = &xs[o * XBSTR + h0];
#pragma unroll
    for (int q = 0; q < 4; ++q)
      *(short8*)(dst + q * 8) = *(const short8*)(src + q * 8);
  }
}

// ---------- Kernel 4: reduce partials, v = squash(cx @ W), emit wvT/out ----
// grid = B*O (4096), block = 256. UNCHANGED from R4 (verified).
__global__ __launch_bounds__(256) void k_v2(
    const ushort* __restrict__ cxp16, const float* __restrict__ W,
    ushort* __restrict__ wvT16, float* __restrict__ out, int final_) {
  __shared__ float Wl[HH * WLSTR];
  __shared__ float cxs[HH];
  __shared__ float red[4][16];
  __shared__ float vres[FF];
  int t = threadIdx.x;
  int blk = blockIdx.x;                 // b*32 + o
  int b = blk >> 5, o = blk & 31;
  int f = t & 15, hq = t >> 4;
#pragma unroll
  for (int j = 0; j < 16; ++j) {
    int h = hq * 16 + j;
    Wl[h * WLSTR + f] = W[(size_t)h * OF + o * FF + f];
  }
  {
    const ushort* cp = cxp16 + (((size_t)b * NP) * OO + o) * HH + t;
    float a = 0.f;
#pragma unroll
    for (int p = 0; p < NP; ++p) a += bf2f(cp[(size_t)p * OO * HH]);
    cxs[t] = a;
  }
  __syncthreads();
  float acc = 0.f;
#pragma unroll
  for (int j = 0; j < 16; ++j)
    acc += cxs[hq * 16 + j] * Wl[(hq * 16 + j) * WLSTR + f];
  acc += __shfl_xor(acc, 16);
  acc += __shfl_xor(acc, 32);
  if ((t & 63) < 16) red[t >> 6][f] = acc;
  __syncthreads();
  if (t < 16) {
    float a2 = red[0][t] + red[1][t] + red[2][t] + red[3][t];
    float n2 = a2 * a2;
#pragma unroll
    for (int mask = 1; mask < 16; mask <<= 1) n2 += __shfl_xor(n2, mask);
    float scale = sqrtf(n2) / (1.f + n2);
    float res = a2 * scale;
    if (final_) out[(size_t)blk * FF + t] = res;
    else vres[t] = res;
  }
  if (!final_) {
    __syncthreads();
    float av = 0.f;
#pragma unroll
    for (int q = 0; q < 16; ++q) av += Wl[t * WLSTR + q] * vres[q];
    wvT16[((size_t)b * OO + o) * HH + t] = f2bf(av);
  }
}

extern "C" void kernel_launch(void* const* d_in, const int* in_sizes, int n_in,
                              void* d_out, int out_size, void* d_ws, size_t ws_size,
                              hipStream_t stream) {
  const float* x = (const float*)d_in[0];  // [128,512,256] fp32
  const float* W = (const float*)d_in[1];  // [1,256,512]   fp32
  float* out = (float*)d_out;              // [128,32,16]   fp32
  float* ws = (float*)d_ws;
  // workspace (float offsets), total ~51 MiB
  float*  xsum_part = ws;                           // 262,144 floats
  ushort* wvT16 = (ushort*)(ws + 262144);           // 1,048,576 ushorts
  ushort* x16   = (ushort*)(ws + 786432);           // 16,777,216 ushorts (swizzled)
  ushort* cxp16 = (ushort*)(ws + 9175040);          // 8,388,608 ushorts

  k_prep<<<BB * NP, 256, 0, stream>>>(x, x16, xsum_part);
  k_v1<<<BB * OO, 256, 0, stream>>>(xsum_part, W, wvT16);
  for (int it = 0; it < 2; ++it) {
    k_route<<<BB * NP, 256, 0, stream>>>(x16, wvT16, cxp16);
    k_v2<<<BB * OO, 256, 0, stream>>>(cxp16, W, wvT16, out, it == 1);
  }
}

// Round 6
// 151.884 us; speedup vs baseline: 1.0331x; 1.0331x over previous
//
#include <hip/hip_runtime.h>

#define BB 128
#define II 512
#define HH 256
#define OO 32
#define FF 16
#define OF 512
#define CI 64          // i-rows per route block
#define NP 8           // partials per b (II / CI)
#define CSTR 72        // c2 LDS row stride (ushorts, 144 B) [R1-verified]
#define WLSTR 17       // W_o LDS row stride (floats, odd -> conflict-free)

typedef __attribute__((ext_vector_type(8))) short short8;   // 8 bf16
typedef __attribute__((ext_vector_type(4))) float floatx4;  // MFMA C/D

__device__ __forceinline__ ushort f2bf(float f) {           // RTN-even
  unsigned u = __float_as_uint(f);
  u += 0x7FFFu + ((u >> 16) & 1u);
  return (ushort)(u >> 16);
}
__device__ __forceinline__ float bf2f(ushort u) {
  return __uint_as_float(((unsigned)u) << 16);
}
// 16B-granule swizzle key for row i (R1-verified bijection).
__device__ __forceinline__ int swzrow(int i) {
  return (i & 7) ^ (((i >> 3) & 3) << 1);
}

// ---------- Kernel 1: x -> bf16 (swizzled) + per-tile column sums ----------
// grid = B*NP (1024), block = 256. UNCHANGED from R1 (verified).
__global__ __launch_bounds__(256) void k_prep(
    const float* __restrict__ x, ushort* __restrict__ x16,
    float* __restrict__ xsum_part) {
  __shared__ float4 red[4][64];
  int t = threadIdx.x;
  int blk = blockIdx.x;                 // b*8 + p
  int c4 = t & 63, grp = t >> 6;
  const float* xg = x + (size_t)blk * CI * HH;
  ushort* x16g = x16 + (size_t)blk * CI * HH;
  int g = c4 >> 1, s4 = (c4 & 1) * 4;
  float4 sum = make_float4(0.f, 0.f, 0.f, 0.f);
#pragma unroll
  for (int j = 0; j < 16; ++j) {
    int row = j * 4 + grp;
    float4 v4 = *(const float4*)(xg + (size_t)row * HH + c4 * 4);
    sum.x += v4.x; sum.y += v4.y; sum.z += v4.z; sum.w += v4.w;
    ushort4 u;
    u.x = f2bf(v4.x); u.y = f2bf(v4.y); u.z = f2bf(v4.z); u.w = f2bf(v4.w);
    *(ushort4*)&x16g[row * HH + (((g ^ swzrow(row)) << 3) + s4)] = u;
  }
  red[grp][c4] = sum;
  __syncthreads();
  if (t < 64) {
    float4 s0 = red[0][t], s1 = red[1][t], s2 = red[2][t], s3 = red[3][t];
    s0.x += s1.x + s2.x + s3.x; s0.y += s1.y + s2.y + s3.y;
    s0.z += s1.z + s2.z + s3.z; s0.w += s1.w + s2.w + s3.w;
    *(float4*)&xsum_part[(size_t)blk * HH + t * 4] = s0;
  }
}

// ---------- Kernel 2: v1 = squash(xsum @ W / 32) -> wvT16 ------------------
// grid = B*O (4096), block = 256. UNCHANGED from R4 (verified).
__global__ __launch_bounds__(256) void k_v1(
    const float* __restrict__ xsum_part, const float* __restrict__ W,
    ushort* __restrict__ wvT16) {
  __shared__ float Wl[HH * WLSTR];      // 17.0 KB
  __shared__ float cxs[HH];
  __shared__ float red[4][16];
  __shared__ float vres[FF];
  int t = threadIdx.x;
  int blk = blockIdx.x;                 // b*32 + o
  int b = blk >> 5, o = blk & 31;
  int f = t & 15, hq = t >> 4;
#pragma unroll
  for (int j = 0; j < 16; ++j) {
    int h = hq * 16 + j;
    Wl[h * WLSTR + f] = W[(size_t)h * OF + o * FF + f];
  }
  {
    const float* cp = xsum_part + (size_t)b * NP * HH + t;
    float a = 0.f;
#pragma unroll
    for (int p = 0; p < NP; ++p) a += cp[(size_t)p * HH];
    cxs[t] = a * (1.0f / 32.0f);
  }
  __syncthreads();
  float acc = 0.f;
#pragma unroll
  for (int j = 0; j < 16; ++j)
    acc += cxs[hq * 16 + j] * Wl[(hq * 16 + j) * WLSTR + f];
  acc += __shfl_xor(acc, 16);
  acc += __shfl_xor(acc, 32);
  if ((t & 63) < 16) red[t >> 6][f] = acc;
  __syncthreads();
  if (t < 16) {
    float a2 = red[0][t] + red[1][t] + red[2][t] + red[3][t];
    float n2 = a2 * a2;
#pragma unroll
    for (int mask = 1; mask < 16; mask <<= 1) n2 += __shfl_xor(n2, mask);
    float scale = sqrtf(n2) / (1.f + n2);
    vres[t] = a2 * scale;
  }
  __syncthreads();
  float av = 0.f;
#pragma unroll
  for (int q = 0; q < 16; ++q) av += Wl[t * WLSTR + q] * vres[q];
  wvT16[((size_t)b * OO + o) * HH + t] = f2bf(av);
}

// ---------- Kernel 3: route: x in LDS, wv B-frags in regs, 4 blocks/CU -----
// grid = B*NP (1024), block = 256 (4 waves), LDS 36.5 KB.
// __launch_bounds__(256,4): VGPR<=128 -> 4 blocks/CU -> all 1024 blocks
// co-resident, no scheduling tail (vs 3/CU = 1.33 waves in R4).
__global__ __launch_bounds__(256, 4) void k_route(
    const ushort* __restrict__ x16, const ushort* __restrict__ wvT16,
    ushort* __restrict__ cxp16) {
  __shared__ alignas(16) ushort xs[CI * HH];     // 32 KB swizzled x tile
  __shared__ alignas(16) ushort c2[OO * CSTR];   // 4.5 KB c[o][i]
  int t = threadIdx.x;
  int blk = blockIdx.x;
  int b = blk >> 3;
  int lane = t & 63, w = t >> 6;
  int l16 = lane & 15, quad = lane >> 4;

  // ---- stage x tile: global (pre-swizzled) -> LDS, linear, 16 B/lane ----
  const ushort* gt = x16 + (size_t)blk * (CI * HH);
#pragma unroll
  for (int it = 0; it < 8; ++it) {
    int off = (it * 4 + w) * 512;       // wave-uniform LDS base (1 KiB/instr)
    __builtin_amdgcn_global_load_lds(
        (const __attribute__((address_space(1))) unsigned*)(gt + off + lane * 8),
        (__attribute__((address_space(3))) unsigned*)(&xs[off]), 16, 0, 0);
  }
  // ---- wv B-fragments -> registers (R5-verified path); L2-hot, latency
  // hides under the same vmcnt(0) as the x staging.
  const ushort* wv0 = wvT16 + ((size_t)b * OO + l16) * HH + quad * 8;
  const ushort* wv1 = wv0 + 16 * HH;
  short8 bfr0[8], bfr1[8];
#pragma unroll
  for (int ks = 0; ks < 8; ++ks) {
    bfr0[ks] = *(const short8*)(wv0 + ks * 32);
    bfr1[ks] = *(const short8*)(wv1 + ks * 32);
  }
  asm volatile("s_waitcnt vmcnt(0)" ::: "memory");
  __syncthreads();

  // ---- GEMM1: D[m=i][n=o] = x . wv^T  (K = h = 256, 8 steps) ----
  int i_a = w * 16 + l16;
  int swa = swzrow(i_a);
  const ushort* xrow = &xs[i_a * HH];
  floatx4 acc0 = {0.f, 0.f, 0.f, 0.f}, acc1 = {0.f, 0.f, 0.f, 0.f};
#pragma unroll
  for (int ks = 0; ks < 8; ++ks) {
    short8 af = *(const short8*)(xrow + (((ks * 4 + quad) ^ swa) << 3));
    acc0 = __builtin_amdgcn_mfma_f32_16x16x32_bf16(af, bfr0[ks], acc0, 0, 0, 0);
    acc1 = __builtin_amdgcn_mfma_f32_16x16x32_bf16(af, bfr1[ks], acc1, 0, 0, 0);
  }
  // ---- softmax over o, in-register (rows i = quad*4+r, col o = l16) ----
#pragma unroll
  for (int r = 0; r < 4; ++r) {
    float a0 = acc0[r], a1 = acc1[r];
    float m = fmaxf(a0, a1);
#pragma unroll
    for (int mask = 1; mask < 16; mask <<= 1) m = fmaxf(m, __shfl_xor(m, mask));
    float e0 = __expf(a0 - m), e1 = __expf(a1 - m);
    float s = e0 + e1;
#pragma unroll
    for (int mask = 1; mask < 16; mask <<= 1) s += __shfl_xor(s, mask);
    float inv = 1.f / s;
    int il = w * 16 + quad * 4 + r;
    c2[l16 * CSTR + il] = f2bf(e0 * inv);
    c2[(16 + l16) * CSTR + il] = f2bf(e1 * inv);
  }
  __syncthreads();

  // ---- phase 3: D[m=o][n=h] = c . xT^T (K = i = 64); R4-verified epilogue --
  short8 caf[2][2];
#pragma unroll
  for (int mt = 0; mt < 2; ++mt)
#pragma unroll
    for (int ks = 0; ks < 2; ++ks)
      caf[mt][ks] = *(const short8*)&c2[(mt * 16 + l16) * CSTR + ks * 32 + quad * 8];
  ushort* outp0 = cxp16 + (size_t)blk * OO * HH;
#pragma unroll
  for (int hi = 0; hi < 4; ++hi) {
    int ht = w * 4 + hi;
    int hh = ht * 16 + l16;
    int gq = hh >> 3, sub = hh & 7;
    floatx4 d0 = {0.f, 0.f, 0.f, 0.f}, d1 = {0.f, 0.f, 0.f, 0.f};
#pragma unroll
    for (int ks = 0; ks < 2; ++ks) {
      short8 bf;
#pragma unroll
      for (int e = 0; e < 8; ++e) {
        int i = ks * 32 + quad * 8 + e;            // swzrow(i) = e ^ (quad<<1)
        bf[e] = (short)xs[i * HH + (((gq ^ e ^ (quad << 1)) << 3) + sub)];
      }
      d0 = __builtin_amdgcn_mfma_f32_16x16x32_bf16(caf[0][ks], bf, d0, 0, 0, 0);
      d1 = __builtin_amdgcn_mfma_f32_16x16x32_bf16(caf[1][ks], bf, d1, 0, 0, 0);
    }
    ushort* outp = outp0 + ht * 16 + l16;
#pragma unroll
    for (int r = 0; r < 4; ++r) {
      outp[(size_t)(quad * 4 + r) * HH] = f2bf(d0[r]);
      outp[(size_t)(16 + quad * 4 + r) * HH] = f2bf(d1[r]);
    }
  }
}

// ---------- Kernel 4: reduce partials, v = squash(cx @ W), emit wvT/out ----
// grid = B*O (4096), block = 256. UNCHANGED from R4 (verified).
__global__ __launch_bounds__(256) void k_v2(
    const ushort* __restrict__ cxp16, const float* __restrict__ W,
    ushort* __restrict__ wvT16, float* __restrict__ out, int final_) {
  __shared__ float Wl[HH * WLSTR];
  __shared__ float cxs[HH];
  __shared__ float red[4][16];
  __shared__ float vres[FF];
  int t = threadIdx.x;
  int blk = blockIdx.x;                 // b*32 + o
  int b = blk >> 5, o = blk & 31;
  int f = t & 15, hq = t >> 4;
#pragma unroll
  for (int j = 0; j < 16; ++j) {
    int h = hq * 16 + j;
    Wl[h * WLSTR + f] = W[(size_t)h * OF + o * FF + f];
  }
  {
    const ushort* cp = cxp16 + (((size_t)b * NP) * OO + o) * HH + t;
    float a = 0.f;
#pragma unroll
    for (int p = 0; p < NP; ++p) a += bf2f(cp[(size_t)p * OO * HH]);
    cxs[t] = a;
  }
  __syncthreads();
  float acc = 0.f;
#pragma unroll
  for (int j = 0; j < 16; ++j)
    acc += cxs[hq * 16 + j] * Wl[(hq * 16 + j) * WLSTR + f];
  acc += __shfl_xor(acc, 16);
  acc += __shfl_xor(acc, 32);
  if ((t & 63) < 16) red[t >> 6][f] = acc;
  __syncthreads();
  if (t < 16) {
    float a2 = red[0][t] + red[1][t] + red[2][t] + red[3][t];
    float n2 = a2 * a2;
#pragma unroll
    for (int mask = 1; mask < 16; mask <<= 1) n2 += __shfl_xor(n2, mask);
    float scale = sqrtf(n2) / (1.f + n2);
    float res = a2 * scale;
    if (final_) out[(size_t)blk * FF + t] = res;
    else vres[t] = res;
  }
  if (!final_) {
    __syncthreads();
    float av = 0.f;
#pragma unroll
    for (int q = 0; q < 16; ++q) av += Wl[t * WLSTR + q] * vres[q];
    wvT16[((size_t)b * OO + o) * HH + t] = f2bf(av);
  }
}

extern "C" void kernel_launch(void* const* d_in, const int* in_sizes, int n_in,
                              void* d_out, int out_size, void* d_ws, size_t ws_size,
                              hipStream_t stream) {
  const float* x = (const float*)d_in[0];  // [128,512,256] fp32
  const float* W = (const float*)d_in[1];  // [1,256,512]   fp32
  float* out = (float*)d_out;              // [128,32,16]   fp32
  float* ws = (float*)d_ws;
  // workspace (float offsets), total ~51 MiB
  float*  xsum_part = ws;                           // 262,144 floats
  ushort* wvT16 = (ushort*)(ws + 262144);           // 1,048,576 ushorts
  ushort* x16   = (ushort*)(ws + 786432);           // 16,777,216 ushorts (swizzled)
  ushort* cxp16 = (ushort*)(ws + 9175040);          // 8,388,608 ushorts

  k_prep<<<BB * NP, 256, 0, stream>>>(x, x16, xsum_part);
  k_v1<<<BB * OO, 256, 0, stream>>>(xsum_part, W, wvT16);
  for (int it = 0; it < 2; ++it) {
    k_route<<<BB * NP, 256, 0, stream>>>(x16, wvT16, cxp16);
    k_v2<<<BB * OO, 256, 0, stream>>>(cxp16, W, wvT16, out, it == 1);
  }
}